// Round 12
// baseline (313.477 us; speedup 1.0000x reference)
//
#include <hip/hip_runtime.h>
#include <hip/hip_bf16.h>

typedef _Float16 h8 __attribute__((ext_vector_type(8)));
typedef __bf16   b8 __attribute__((ext_vector_type(8)));
typedef float    f4 __attribute__((ext_vector_type(4)));

#define B_    4
#define S_    4096
#define D_    512
#define ROWS_ (B_ * S_)          // 16384
#define NQKV_ 1536
#define BR    64                 // q-rows per block
#define BC2   64                 // keys per iteration
#define NIT2  (S_ / BC2)         // 64
#define KP3   520                // K LDS pitch (f16): 1040B/row, 16B-ALIGNED (R8 lesson)
#define KT3   (BC2 * KP3)
#define PP3   72                 // P LDS pitch (bf16): 144B/row, 16B-ALIGNED
#define MSH   (30.0f * 1.4426950408889634f)   // fixed softmax shift (log2 units)
#define L2E   1.4426950408889634f

// async global->LDS, 16B per lane; dst is wave-uniform base (+lane*16 implied)
__device__ __forceinline__ void gl_lds16(const void* src, void* dst) {
    __builtin_amdgcn_global_load_lds(
        (const __attribute__((address_space(1))) unsigned int*)src,
        (__attribute__((address_space(3))) unsigned int*)dst, 16, 0, 0);
}

// ---------------------------------------------------------------- convert ---
__global__ __launch_bounds__(256) void convert_all(
    const float* __restrict__ x,
    const float* __restrict__ Wq, const float* __restrict__ Wk, const float* __restrict__ Wv,
    const float* __restrict__ bq, const float* __restrict__ bk, const float* __restrict__ bv,
    const float* __restrict__ Wo,
    _Float16* __restrict__ xh, _Float16* __restrict__ wqkvT, _Float16* __restrict__ woT,
    float* __restrict__ bqkv)
{
    long i0 = (long)blockIdx.x * blockDim.x + threadIdx.x;
    long stride = (long)gridDim.x * blockDim.x;
    const long NX  = (long)ROWS_ * D_;
    const long NW  = (long)D_ * NQKV_;
    const long NWO = (long)D_ * D_;

    for (long i = i0; i < NX; i += stride) xh[i] = (_Float16)x[i];

    for (long i = i0; i < NW; i += stride) {
        long n = i >> 9, k = i & 511;
        long which = n >> 9, nn = n & 511;
        const float* W = (which == 0) ? Wq : (which == 1) ? Wk : Wv;
        wqkvT[i] = (_Float16)W[k * 512 + nn];
    }
    for (long i = i0; i < NWO; i += stride) {
        long n = i >> 9, k = i & 511;
        woT[i] = (_Float16)Wo[k * 512 + n];
    }
    for (long i = i0; i < NQKV_; i += stride) {
        long which = i >> 9, nn = i & 511;
        const float* bb = (which == 0) ? bq : (which == 1) ? bk : bv;
        bqkv[i] = bb[nn];
    }
}

// ------------------------------------------------------------------- GEMM ---
// 128x256 tile, 8 waves (512 thr), 2-PHASE DOUBLE-BUFFERED staging (T3-min):
// stage(t+1) into buf^1 is issued BEFORE compute(t), so the 3 gl_lds16 fly
// during the 16 MFMAs + cross-wave overlap instead of being drained cold
// (previous structure: barrier -> load -> barrier(drain) -> MFMA = zero
// latency cover on every one of the 16 K-steps).
// Hazards: reads(t-1) of buf^1 retire at barrier(t-1) (lgkmcnt 0) before
// DMA(t+1) writes buf^1; DMA(t+1) retires at barrier(t) (vmcnt 0, placed
// AFTER the MFMAs) before reads(t+1).  One barrier per K-step.
// For QKV (OUT_F16, vPout != null): col0 >= 1024 tiles are the V projection;
// epilogue writes fragment-major vP directly:
// vP[((b*128+kt)*32+dt)*512 + (q*16+l)*8 + k3] = V[b][s][d],
// kt=s>>5, q=(s>>3)&3, k3=s&7, dt=d>>4, l=d&15.  (col0 multiple of 256 ->
// the 1024 boundary is tile-aligned.)
template <bool OUT_F16>
__global__ __launch_bounds__(512) void gemm_bt(
    const _Float16* __restrict__ A, const _Float16* __restrict__ BT,
    const float* __restrict__ bias, void* __restrict__ Cout,
    int M, int N, int K, __bf16* __restrict__ vPout)
{
    __shared__ _Float16 As[2][128 * 32];    // 2 x 8 KB
    __shared__ _Float16 Bs[2][256 * 32];    // 2 x 16 KB

    int tid = threadIdx.x;
    int w = tid >> 6, lane = tid & 63, quad = lane >> 4, l16 = lane & 15;
    long row0 = (long)blockIdx.x * 128, col0 = (long)blockIdx.y * 256;
    int wr = (w >> 2) * 64, wc = (w & 3) * 64;

    f4 acc[4][4];
    for (int i = 0; i < 4; i++)
        for (int j = 0; j < 4; j++) acc[i][j] = (f4){0.f, 0.f, 0.f, 0.f};

    const int lrow = lane >> 2;          // staging row within 16-row segment
    const int lcol = (lane & 3) * 8;     // staging col (f16)
    const int NT = K >> 5;               // K-steps

    // prologue: stage t=0 into buf 0
    gl_lds16(A  + (row0 + w * 16 + lrow) * K + lcol,        As[0] + w * 512);
    gl_lds16(BT + (col0 + w * 16 + lrow) * K + lcol,        Bs[0] + w * 512);
    gl_lds16(BT + (col0 + (w + 8) * 16 + lrow) * K + lcol,  Bs[0] + (w + 8) * 512);
    __syncthreads();    // drains vmcnt -> buf0 resident

    for (int t = 0; t < NT; ++t) {
        const int cur = t & 1;
        if (t + 1 < NT) {
            const int k1 = (t + 1) * 32;
            gl_lds16(A  + (row0 + w * 16 + lrow) * K + k1 + lcol,        As[cur ^ 1] + w * 512);
            gl_lds16(BT + (col0 + w * 16 + lrow) * K + k1 + lcol,        Bs[cur ^ 1] + w * 512);
            gl_lds16(BT + (col0 + (w + 8) * 16 + lrow) * K + k1 + lcol,  Bs[cur ^ 1] + (w + 8) * 512);
        }
        h8 af[4], bf[4];
        for (int i = 0; i < 4; i++) af[i] = *(const h8*)(As[cur] + (wr + i * 16 + l16) * 32 + quad * 8);
        for (int j = 0; j < 4; j++) bf[j] = *(const h8*)(Bs[cur] + (wc + j * 16 + l16) * 32 + quad * 8);
        for (int i = 0; i < 4; i++)
            for (int j = 0; j < 4; j++)
                acc[i][j] = __builtin_amdgcn_mfma_f32_16x16x32_f16(af[i], bf[j], acc[i][j], 0, 0, 0);
        __builtin_amdgcn_sched_barrier(0);
        asm volatile("s_waitcnt vmcnt(0)");     // stage(t+1) landed (flew over MFMAs)
        asm volatile("s_waitcnt lgkmcnt(0)");   // frag reads of buf[cur] retired
        __builtin_amdgcn_s_barrier();
        __builtin_amdgcn_sched_barrier(0);
    }

    if (OUT_F16 && vPout != nullptr && col0 >= 1024) {
        for (int i = 0; i < 4; i++) {
            long row = row0 + wr + i * 16 + quad * 4;   // +r
            int bb   = (int)(row >> 12);
            int s    = (int)(row & 4095);
            int kt32 = s >> 5;
            int qq   = (s >> 3) & 3;
            int k3   = s & 7;            // = (quad&1)*4; +r gives consecutive k3
            for (int j = 0; j < 4; j++) {
                int dglob = (int)(col0 - 1024) + wc + j * 16;
                int dt = dglob >> 4;
                long off = (((long)bb * 128 + kt32) * 32 + dt) * 512
                         + (qq * 16 + l16) * 8 + k3;
                union { __bf16 h[4]; uint2 u2; } pk;
                for (int r = 0; r < 4; r++)
                    pk.h[r] = (__bf16)(acc[i][j][r] + bias[col0 + wc + j * 16 + l16]);
                *(uint2*)(vPout + off) = pk.u2;
            }
        }
    } else {
        for (int i = 0; i < 4; i++)
            for (int j = 0; j < 4; j++)
                for (int r = 0; r < 4; r++) {
                    long row = row0 + wr + i * 16 + quad * 4 + r;
                    long col = col0 + wc + j * 16 + l16;
                    float v = acc[i][j][r] + bias[col];
                    if (OUT_F16) ((_Float16*)Cout)[row * N + col] = (_Float16)v;
                    else         ((float*)Cout)[row * N + col]    = v;
                }
    }
}

// -------------------------------------------------------- flash attention ---
// REVERTED to the R10 8-wave producer/consumer kernel (measured 168.1 us,
// conflicts 1.049e7).  R11's 16-wave variant doubled occupancy (22->44%)
// with ZERO speedup (and doubled kb redundancy) -> occupancy is not the
// limiter; this structure is at its practical floor.
__global__ __launch_bounds__(512, 2) void attn_kernel(const _Float16* __restrict__ qkv,
                                                      const __bf16* __restrict__ vP,
                                                      _Float16* __restrict__ yb)
{
    __shared__ _Float16 Ks[2 * KT3];        // 133120 B
    __shared__ __bf16   Ps[2 * BR * PP3];   // 18432 B
    __shared__ float    lpart[2][BR];       // 512 B

    const int tid = threadIdx.x;
    const int w = tid >> 6, lane = tid & 63, quad = lane >> 4, l16 = lane & 15;

    // ---- batch->XCD affinity swizzle (bijective over 256 blocks)
    const int bid = blockIdx.x;
    const int xcd = bid & 7;
    const int b = xcd >> 1;
    const long q0 = (long)((xcd & 1) * 32 + (bid >> 3)) * BR;
    const long rowBase = (long)b * S_;

    const _Float16* kbase = qkv + rowBase * NQKV_ + 512;

    // ---- prologue: all 8 waves stage K tile 0 (wave w: rows w*8..w*8+7)
#pragma unroll
    for (int i = 0; i < 8; i++) {
        int r = w * 8 + i;
        gl_lds16(kbase + (long)r * NQKV_ + lane * 8, Ks + r * KP3);
    }

    if (w < 4) {
        // ==================================================== PRODUCER ====
        const int rs0 = (w & 1) * 32;       // first row of this wave's strips
        const int kg0 = (w >> 1) * 32;      // first key of this wave's groups

        h8 Qf0[16], Qf1[16];
        {
            const _Float16* q0p = qkv + (rowBase + q0 + rs0 + l16) * NQKV_;
            const _Float16* q1p = q0p + 16 * NQKV_;
#pragma unroll
            for (int ks = 0; ks < 16; ks++) {
                Qf0[ks] = *(const h8*)(q0p + ks * 32 + quad * 8);
                Qf1[ks] = *(const h8*)(q1p + ks * 32 + quad * 8);
            }
        }
        float lo0[4] = {0.f, 0.f, 0.f, 0.f};
        float lo1[4] = {0.f, 0.f, 0.f, 0.f};

        __syncthreads();    // prologue barrier (full drain: K0 landed)

        for (int kt = 0; kt < NIT2; kt++) {
            if (kt + 1 < NIT2) {
                const _Float16* kn = kbase + (long)(kt + 1) * BC2 * NQKV_;
                _Float16* kd = Ks + ((kt + 1) & 1) * KT3;
#pragma unroll
                for (int i = 0; i < 8; i++) {
                    int r = w * 8 + i;
                    gl_lds16(kn + (long)r * NQKV_ + lane * 8, kd + r * KP3);
                }
            }
            f4 S[2][2][2];      // [rowstrip][keygroup][k-chain]
#pragma unroll
            for (int a = 0; a < 2; a++)
#pragma unroll
                for (int c = 0; c < 2; c++)
#pragma unroll
                    for (int d = 0; d < 2; d++) S[a][c][d] = (f4){0.f, 0.f, 0.f, 0.f};
            const _Float16* kr0 = Ks + (kt & 1) * KT3 + (kg0 + l16) * KP3 + quad * 8;
            const _Float16* kr1 = kr0 + 16 * KP3;
            __builtin_amdgcn_s_setprio(1);
#pragma unroll
            for (int ks = 0; ks < 8; ks++) {
                h8 a0 = *(const h8*)(kr0 + ks * 32);
                h8 a1 = *(const h8*)(kr0 + (ks + 8) * 32);
                h8 c0 = *(const h8*)(kr1 + ks * 32);
                h8 c1 = *(const h8*)(kr1 + (ks + 8) * 32);
                S[0][0][0] = __builtin_amdgcn_mfma_f32_16x16x32_f16(Qf0[ks],     a0, S[0][0][0], 0, 0, 0);
                S[1][0][0] = __builtin_amdgcn_mfma_f32_16x16x32_f16(Qf1[ks],     a0, S[1][0][0], 0, 0, 0);
                S[0][1][0] = __builtin_amdgcn_mfma_f32_16x16x32_f16(Qf0[ks],     c0, S[0][1][0], 0, 0, 0);
                S[1][1][0] = __builtin_amdgcn_mfma_f32_16x16x32_f16(Qf1[ks],     c0, S[1][1][0], 0, 0, 0);
                S[0][0][1] = __builtin_amdgcn_mfma_f32_16x16x32_f16(Qf0[ks + 8], a1, S[0][0][1], 0, 0, 0);
                S[1][0][1] = __builtin_amdgcn_mfma_f32_16x16x32_f16(Qf1[ks + 8], a1, S[1][0][1], 0, 0, 0);
                S[0][1][1] = __builtin_amdgcn_mfma_f32_16x16x32_f16(Qf0[ks + 8], c1, S[0][1][1], 0, 0, 0);
                S[1][1][1] = __builtin_amdgcn_mfma_f32_16x16x32_f16(Qf1[ks + 8], c1, S[1][1][1], 0, 0, 0);
            }
            __builtin_amdgcn_s_setprio(0);
            __bf16* ps = Ps + (kt & 1) * (BR * PP3);
#pragma unroll
            for (int r = 0; r < 4; r++) {
                float p00 = exp2f((S[0][0][0][r] + S[0][0][1][r]) * L2E - MSH);
                float p01 = exp2f((S[0][1][0][r] + S[0][1][1][r]) * L2E - MSH);
                float p10 = exp2f((S[1][0][0][r] + S[1][0][1][r]) * L2E - MSH);
                float p11 = exp2f((S[1][1][0][r] + S[1][1][1][r]) * L2E - MSH);
                __bf16 b00 = (__bf16)p00, b01 = (__bf16)p01;
                __bf16 b10 = (__bf16)p10, b11 = (__bf16)p11;
                int r0 = (rs0 + quad * 4 + r) * PP3;
                int r1 = (rs0 + 16 + quad * 4 + r) * PP3;
                ps[r0 + kg0 + l16]      = b00;
                ps[r0 + kg0 + 16 + l16] = b01;
                ps[r1 + kg0 + l16]      = b10;
                ps[r1 + kg0 + 16 + l16] = b11;
                lo0[r] += (float)b00 + (float)b01;
                lo1[r] += (float)b10 + (float)b11;
            }
            __builtin_amdgcn_sched_barrier(0);
            asm volatile("s_waitcnt vmcnt(0)");     // DMA(kt+1) retired
            asm volatile("s_waitcnt lgkmcnt(0)");   // Ps published
            __builtin_amdgcn_s_barrier();
            __builtin_amdgcn_sched_barrier(0);
        }

        // epilogue: reduce l over the 16 key-column lanes, publish
#pragma unroll
        for (int r = 0; r < 4; r++)
#pragma unroll
            for (int m = 1; m < 16; m <<= 1) {
                lo0[r] += __shfl_xor(lo0[r], m, 16);
                lo1[r] += __shfl_xor(lo1[r], m, 16);
            }
        if (l16 == 0)
            for (int r = 0; r < 4; r++) {
                lpart[w >> 1][rs0 + quad * 4 + r]      = lo0[r];
                lpart[w >> 1][rs0 + 16 + quad * 4 + r] = lo1[r];
            }
        __syncthreads();    // epilogue barrier (publishes lpart)
    } else {
        // ==================================================== CONSUMER ====
        const int cv = w - 4;               // d-range cv*128 .. cv*128+127
        const __bf16* vpbase = vP + ((long)b * 128 * 32 + cv * 8) * 512 + lane * 8;

        f4 O[4][8];
#pragma unroll
        for (int rt = 0; rt < 4; rt++)
#pragma unroll
            for (int ct = 0; ct < 8; ct++) O[rt][ct] = (f4){0.f, 0.f, 0.f, 0.f};
        b8 vreg[16];

        __syncthreads();    // prologue barrier

        for (int kt = 0; kt < NIT2; kt++) {
            // a) DMA(kt+1) first (must be OLDER than V(kt) for the vmcnt(16))
            if (kt + 1 < NIT2) {
                const _Float16* kn = kbase + (long)(kt + 1) * BC2 * NQKV_;
                _Float16* kd = Ks + ((kt + 1) & 1) * KT3;
#pragma unroll
                for (int i = 0; i < 8; i++) {
                    int r = w * 8 + i;
                    gl_lds16(kn + (long)r * NQKV_ + lane * 8, kd + r * KP3);
                }
            }
            __builtin_amdgcn_sched_barrier(0);   // pin DMA-before-V issue order
            // b) PV(kt-1): wait V(kt-1) resident, then 64 MFMA
            if (kt > 0) {
                if (kt < NIT2 - 1) asm volatile("s_waitcnt vmcnt(8)");  // retires V(kt-1)
                else               asm volatile("s_waitcnt vmcnt(0)");  // no DMA issued
                const __bf16* ps = Ps + ((kt - 1) & 1) * (BR * PP3);
                __builtin_amdgcn_s_setprio(1);
#pragma unroll
                for (int rt = 0; rt < 4; rt++) {
                    b8 pa0 = *(const b8*)(ps + (rt * 16 + l16) * PP3 + quad * 8);
                    b8 pa1 = *(const b8*)(ps + (rt * 16 + l16) * PP3 + 32 + quad * 8);
#pragma unroll
                    for (int ct = 0; ct < 8; ct++) {
                        O[rt][ct] = __builtin_amdgcn_mfma_f32_16x16x32_bf16(pa0, vreg[ct],     O[rt][ct], 0, 0, 0);
                        O[rt][ct] = __builtin_amdgcn_mfma_f32_16x16x32_bf16(pa1, vreg[8 + ct], O[rt][ct], 0, 0, 0);
                    }
                }
                __builtin_amdgcn_s_setprio(0);
            }
            // c) issue V(kt): two 32-key fragment tiles, contiguous 8KB/wave
            {
                const __bf16* vs0 = vpbase + (long)(2 * kt) * (32 * 512);
#pragma unroll
                for (int ct = 0; ct < 8; ct++) {
                    vreg[ct]     = *(const b8*)(vs0 + ct * 512);
                    vreg[8 + ct] = *(const b8*)(vs0 + 32 * 512 + ct * 512);
                }
            }
            __builtin_amdgcn_sched_barrier(0);
            asm volatile("s_waitcnt vmcnt(16)");    // retire DMA(kt+1); V(kt) flies
            asm volatile("s_waitcnt lgkmcnt(0)");   // pa reads retired
            __builtin_amdgcn_s_barrier();
            __builtin_amdgcn_sched_barrier(0);
        }
        // final PV(NIT2-1)
        asm volatile("s_waitcnt vmcnt(0)");
        {
            const __bf16* ps = Ps + ((NIT2 - 1) & 1) * (BR * PP3);
#pragma unroll
            for (int rt = 0; rt < 4; rt++) {
                b8 pa0 = *(const b8*)(ps + (rt * 16 + l16) * PP3 + quad * 8);
                b8 pa1 = *(const b8*)(ps + (rt * 16 + l16) * PP3 + 32 + quad * 8);
#pragma unroll
                for (int ct = 0; ct < 8; ct++) {
                    O[rt][ct] = __builtin_amdgcn_mfma_f32_16x16x32_bf16(pa0, vreg[ct],     O[rt][ct], 0, 0, 0);
                    O[rt][ct] = __builtin_amdgcn_mfma_f32_16x16x32_bf16(pa1, vreg[8 + ct], O[rt][ct], 0, 0, 0);
                }
            }
        }
        __syncthreads();    // epilogue barrier (lpart visible)

#pragma unroll
        for (int rt = 0; rt < 4; rt++) {
            f4 l0 = *(const f4*)(&lpart[0][rt * 16 + quad * 4]);
            f4 l1 = *(const f4*)(&lpart[1][rt * 16 + quad * 4]);
            float li[4];
            for (int r = 0; r < 4; r++) li[r] = 1.f / (l0[r] + l1[r]);
            for (int ct = 0; ct < 8; ct++)
                for (int r = 0; r < 4; r++) {
                    long row = rowBase + q0 + rt * 16 + quad * 4 + r;
                    long col = cv * 128 + ct * 16 + l16;
                    yb[row * 512 + col] = (_Float16)(O[rt][ct][r] * li[r]);
                }
        }
    }
}

// ----------------------------------------------------------------- launch ---
extern "C" void kernel_launch(void* const* d_in, const int* in_sizes, int n_in,
                              void* d_out, int out_size, void* d_ws, size_t ws_size,
                              hipStream_t stream)
{
    const float* x  = (const float*)d_in[0];
    const float* Wq = (const float*)d_in[1];
    const float* bq = (const float*)d_in[2];
    const float* Wk = (const float*)d_in[3];
    const float* bk = (const float*)d_in[4];
    const float* Wv = (const float*)d_in[5];
    const float* bv = (const float*)d_in[6];
    const float* Wo = (const float*)d_in[7];
    const float* bo = (const float*)d_in[8];
    float* out = (float*)d_out;

    char* ws = (char*)d_ws;
    _Float16* xh    = (_Float16*)(ws);                  // 16 MB
    _Float16* qkv   = (_Float16*)(ws + 16777216);       // 48 MB  [16384][1536] (V third unused)
    __bf16*   vP    = (__bf16*)(ws + 67108864);         // 16 MB  packed V (written by gemm1)
    _Float16* yb    = (_Float16*)(ws + 83886080);       // 16 MB  [16384][512]
    _Float16* wqkvT = (_Float16*)(ws + 100663296);      // 1.5 MB
    _Float16* woT   = (_Float16*)(ws + 102236160);      // 0.5 MB
    float*    bqkv  = (float*)(ws + 102760448);         // 6 KB

    convert_all<<<2048, 256, 0, stream>>>(x, Wq, Wk, Wv, bq, bk, bv, Wo,
                                          xh, wqkvT, woT, bqkv);

    dim3 g1(128, 6);
    gemm_bt<true><<<g1, 512, 0, stream>>>(xh, wqkvT, bqkv, qkv, ROWS_, NQKV_, D_, vP);

    attn_kernel<<<256, 512, 0, stream>>>(qkv, vP, yb);

    dim3 g2(128, 2);
    gemm_bt<false><<<g2, 512, 0, stream>>>(yb, woT, bo, out, ROWS_, D_, D_, nullptr);
}

// Round 13
// 295.685 us; speedup vs baseline: 1.0602x; 1.0602x over previous
//
#include <hip/hip_runtime.h>
#include <hip/hip_bf16.h>

typedef _Float16 h8 __attribute__((ext_vector_type(8)));
typedef __bf16   b8 __attribute__((ext_vector_type(8)));
typedef float    f4 __attribute__((ext_vector_type(4)));

#define B_    4
#define S_    4096
#define D_    512
#define ROWS_ (B_ * S_)          // 16384
#define NQKV_ 1536
#define BR    64                 // q-rows per block
#define BC2   64                 // keys per iteration
#define NIT2  (S_ / BC2)         // 64
#define KP3   520                // K LDS pitch (f16): 1040B/row, 16B-ALIGNED (R8 lesson)
#define KT3   (BC2 * KP3)
#define PP3   72                 // P LDS pitch (bf16): 144B/row, 16B-ALIGNED
#define YP    520                // y epilogue LDS pitch (f16), 16B-aligned
#define MSH   (30.0f * 1.4426950408889634f)   // fixed softmax shift (log2 units)
#define L2E   1.4426950408889634f

// async global->LDS, 16B per lane; dst is wave-uniform base (+lane*16 implied)
__device__ __forceinline__ void gl_lds16(const void* src, void* dst) {
    __builtin_amdgcn_global_load_lds(
        (const __attribute__((address_space(1))) unsigned int*)src,
        (__attribute__((address_space(3))) unsigned int*)dst, 16, 0, 0);
}

// ---------------------------------------------------------------- convert ---
__global__ __launch_bounds__(256) void convert_all(
    const float* __restrict__ x,
    const float* __restrict__ Wq, const float* __restrict__ Wk, const float* __restrict__ Wv,
    const float* __restrict__ bq, const float* __restrict__ bk, const float* __restrict__ bv,
    const float* __restrict__ Wo,
    _Float16* __restrict__ xh, _Float16* __restrict__ wqkvT, _Float16* __restrict__ woT,
    float* __restrict__ bqkv)
{
    long i0 = (long)blockIdx.x * blockDim.x + threadIdx.x;
    long stride = (long)gridDim.x * blockDim.x;
    const long NX  = (long)ROWS_ * D_;
    const long NW  = (long)D_ * NQKV_;
    const long NWO = (long)D_ * D_;

    for (long i = i0; i < NX; i += stride) xh[i] = (_Float16)x[i];

    for (long i = i0; i < NW; i += stride) {
        long n = i >> 9, k = i & 511;
        long which = n >> 9, nn = n & 511;
        const float* W = (which == 0) ? Wq : (which == 1) ? Wk : Wv;
        wqkvT[i] = (_Float16)W[k * 512 + nn];
    }
    for (long i = i0; i < NWO; i += stride) {
        long n = i >> 9, k = i & 511;
        woT[i] = (_Float16)Wo[k * 512 + n];
    }
    for (long i = i0; i < NQKV_; i += stride) {
        long which = i >> 9, nn = i & 511;
        const float* bb = (which == 0) ? bq : (which == 1) ? bk : bv;
        bqkv[i] = bb[nn];
    }
}

// ------------------------------------------------------------------- GEMM ---
// 128x256 tile, 8 waves, 2-phase double-buffered gl_lds16 staging (R12).
// Used only for the QKV projection now (output projection fused into attn).
// col0 >= 1024 tiles are the V projection; epilogue writes fragment-major vP:
// vP[((b*128+kt)*32+dt)*512 + (q*16+l)*8 + k3] = V[b][s][d],
// kt=s>>5, q=(s>>3)&3, k3=s&7, dt=d>>4, l=d&15.
template <bool OUT_F16>
__global__ __launch_bounds__(512) void gemm_bt(
    const _Float16* __restrict__ A, const _Float16* __restrict__ BT,
    const float* __restrict__ bias, void* __restrict__ Cout,
    int M, int N, int K, __bf16* __restrict__ vPout)
{
    __shared__ _Float16 As[2][128 * 32];    // 2 x 8 KB
    __shared__ _Float16 Bs[2][256 * 32];    // 2 x 16 KB

    int tid = threadIdx.x;
    int w = tid >> 6, lane = tid & 63, quad = lane >> 4, l16 = lane & 15;
    long row0 = (long)blockIdx.x * 128, col0 = (long)blockIdx.y * 256;
    int wr = (w >> 2) * 64, wc = (w & 3) * 64;

    f4 acc[4][4];
    for (int i = 0; i < 4; i++)
        for (int j = 0; j < 4; j++) acc[i][j] = (f4){0.f, 0.f, 0.f, 0.f};

    const int lrow = lane >> 2;          // staging row within 16-row segment
    const int lcol = (lane & 3) * 8;     // staging col (f16)
    const int NT = K >> 5;               // K-steps

    // prologue: stage t=0 into buf 0
    gl_lds16(A  + (row0 + w * 16 + lrow) * K + lcol,        As[0] + w * 512);
    gl_lds16(BT + (col0 + w * 16 + lrow) * K + lcol,        Bs[0] + w * 512);
    gl_lds16(BT + (col0 + (w + 8) * 16 + lrow) * K + lcol,  Bs[0] + (w + 8) * 512);
    __syncthreads();    // drains vmcnt -> buf0 resident

    for (int t = 0; t < NT; ++t) {
        const int cur = t & 1;
        if (t + 1 < NT) {
            const int k1 = (t + 1) * 32;
            gl_lds16(A  + (row0 + w * 16 + lrow) * K + k1 + lcol,        As[cur ^ 1] + w * 512);
            gl_lds16(BT + (col0 + w * 16 + lrow) * K + k1 + lcol,        Bs[cur ^ 1] + w * 512);
            gl_lds16(BT + (col0 + (w + 8) * 16 + lrow) * K + k1 + lcol,  Bs[cur ^ 1] + (w + 8) * 512);
        }
        h8 af[4], bf[4];
        for (int i = 0; i < 4; i++) af[i] = *(const h8*)(As[cur] + (wr + i * 16 + l16) * 32 + quad * 8);
        for (int j = 0; j < 4; j++) bf[j] = *(const h8*)(Bs[cur] + (wc + j * 16 + l16) * 32 + quad * 8);
        for (int i = 0; i < 4; i++)
            for (int j = 0; j < 4; j++)
                acc[i][j] = __builtin_amdgcn_mfma_f32_16x16x32_f16(af[i], bf[j], acc[i][j], 0, 0, 0);
        __builtin_amdgcn_sched_barrier(0);
        asm volatile("s_waitcnt vmcnt(0)");     // stage(t+1) landed (flew over MFMAs)
        asm volatile("s_waitcnt lgkmcnt(0)");   // frag reads of buf[cur] retired
        __builtin_amdgcn_s_barrier();
        __builtin_amdgcn_sched_barrier(0);
    }

    if (OUT_F16 && vPout != nullptr && col0 >= 1024) {
        for (int i = 0; i < 4; i++) {
            long row = row0 + wr + i * 16 + quad * 4;   // +r
            int bb   = (int)(row >> 12);
            int s    = (int)(row & 4095);
            int kt32 = s >> 5;
            int qq   = (s >> 3) & 3;
            int k3   = s & 7;            // = (quad&1)*4; +r gives consecutive k3
            for (int j = 0; j < 4; j++) {
                int dglob = (int)(col0 - 1024) + wc + j * 16;
                int dt = dglob >> 4;
                long off = (((long)bb * 128 + kt32) * 32 + dt) * 512
                         + (qq * 16 + l16) * 8 + k3;
                union { __bf16 h[4]; uint2 u2; } pk;
                for (int r = 0; r < 4; r++)
                    pk.h[r] = (__bf16)(acc[i][j][r] + bias[col0 + wc + j * 16 + l16]);
                *(uint2*)(vPout + off) = pk.u2;
            }
        }
    } else {
        for (int i = 0; i < 4; i++)
            for (int j = 0; j < 4; j++)
                for (int r = 0; r < 4; r++) {
                    long row = row0 + wr + i * 16 + quad * 4 + r;
                    long col = col0 + wc + j * 16 + l16;
                    float v = acc[i][j][r] + bias[col];
                    if (OUT_F16) ((_Float16*)Cout)[row * N + col] = (_Float16)v;
                    else         ((float*)Cout)[row * N + col]    = v;
                }
    }
}

// -------------------------------------------------------- flash attention ---
// R10 8-wave producer/consumer main loop (verified, ~170 us) + FUSED OUTPUT
// PROJECTION epilogue: y (64x512, in consumer regs) -> LDS (reusing Ks,
// dead after the last in-loop barrier) -> all 8 waves compute
// out[64x512] = y @ woT^T + bo (256 MFMA/wave, K=512) and store f32.
// Deletes the gemm2 dispatch + the 32 MB yb round-trip.
__global__ __launch_bounds__(512, 2) void attn_kernel(const _Float16* __restrict__ qkv,
                                                      const __bf16* __restrict__ vP,
                                                      const _Float16* __restrict__ woT,
                                                      const float* __restrict__ bo,
                                                      float* __restrict__ out)
{
    __shared__ _Float16 Ks[2 * KT3];        // 133120 B (reused as y_lds in epilogue)
    __shared__ __bf16   Ps[2 * BR * PP3];   // 18432 B
    __shared__ float    lpart[2][BR];       // 512 B

    const int tid = threadIdx.x;
    const int w = tid >> 6, lane = tid & 63, quad = lane >> 4, l16 = lane & 15;

    // ---- batch->XCD affinity swizzle (bijective over 256 blocks)
    const int bid = blockIdx.x;
    const int xcd = bid & 7;
    const int b = xcd >> 1;
    const long q0 = (long)((xcd & 1) * 32 + (bid >> 3)) * BR;
    const long rowBase = (long)b * S_;

    const _Float16* kbase = qkv + rowBase * NQKV_ + 512;

    // ---- prologue: all 8 waves stage K tile 0 (wave w: rows w*8..w*8+7)
#pragma unroll
    for (int i = 0; i < 8; i++) {
        int r = w * 8 + i;
        gl_lds16(kbase + (long)r * NQKV_ + lane * 8, Ks + r * KP3);
    }

    if (w < 4) {
        // ==================================================== PRODUCER ====
        const int rs0 = (w & 1) * 32;       // first row of this wave's strips
        const int kg0 = (w >> 1) * 32;      // first key of this wave's groups

        h8 Qf0[16], Qf1[16];
        {
            const _Float16* q0p = qkv + (rowBase + q0 + rs0 + l16) * NQKV_;
            const _Float16* q1p = q0p + 16 * NQKV_;
#pragma unroll
            for (int ks = 0; ks < 16; ks++) {
                Qf0[ks] = *(const h8*)(q0p + ks * 32 + quad * 8);
                Qf1[ks] = *(const h8*)(q1p + ks * 32 + quad * 8);
            }
        }
        float lo0[4] = {0.f, 0.f, 0.f, 0.f};
        float lo1[4] = {0.f, 0.f, 0.f, 0.f};

        __syncthreads();    // prologue barrier (full drain: K0 landed)

        for (int kt = 0; kt < NIT2; kt++) {
            if (kt + 1 < NIT2) {
                const _Float16* kn = kbase + (long)(kt + 1) * BC2 * NQKV_;
                _Float16* kd = Ks + ((kt + 1) & 1) * KT3;
#pragma unroll
                for (int i = 0; i < 8; i++) {
                    int r = w * 8 + i;
                    gl_lds16(kn + (long)r * NQKV_ + lane * 8, kd + r * KP3);
                }
            }
            f4 S[2][2][2];      // [rowstrip][keygroup][k-chain]
#pragma unroll
            for (int a = 0; a < 2; a++)
#pragma unroll
                for (int c = 0; c < 2; c++)
#pragma unroll
                    for (int d = 0; d < 2; d++) S[a][c][d] = (f4){0.f, 0.f, 0.f, 0.f};
            const _Float16* kr0 = Ks + (kt & 1) * KT3 + (kg0 + l16) * KP3 + quad * 8;
            const _Float16* kr1 = kr0 + 16 * KP3;
            __builtin_amdgcn_s_setprio(1);
#pragma unroll
            for (int ks = 0; ks < 8; ks++) {
                h8 a0 = *(const h8*)(kr0 + ks * 32);
                h8 a1 = *(const h8*)(kr0 + (ks + 8) * 32);
                h8 c0 = *(const h8*)(kr1 + ks * 32);
                h8 c1 = *(const h8*)(kr1 + (ks + 8) * 32);
                S[0][0][0] = __builtin_amdgcn_mfma_f32_16x16x32_f16(Qf0[ks],     a0, S[0][0][0], 0, 0, 0);
                S[1][0][0] = __builtin_amdgcn_mfma_f32_16x16x32_f16(Qf1[ks],     a0, S[1][0][0], 0, 0, 0);
                S[0][1][0] = __builtin_amdgcn_mfma_f32_16x16x32_f16(Qf0[ks],     c0, S[0][1][0], 0, 0, 0);
                S[1][1][0] = __builtin_amdgcn_mfma_f32_16x16x32_f16(Qf1[ks],     c0, S[1][1][0], 0, 0, 0);
                S[0][0][1] = __builtin_amdgcn_mfma_f32_16x16x32_f16(Qf0[ks + 8], a1, S[0][0][1], 0, 0, 0);
                S[1][0][1] = __builtin_amdgcn_mfma_f32_16x16x32_f16(Qf1[ks + 8], a1, S[1][0][1], 0, 0, 0);
                S[0][1][1] = __builtin_amdgcn_mfma_f32_16x16x32_f16(Qf0[ks + 8], c1, S[0][1][1], 0, 0, 0);
                S[1][1][1] = __builtin_amdgcn_mfma_f32_16x16x32_f16(Qf1[ks + 8], c1, S[1][1][1], 0, 0, 0);
            }
            __builtin_amdgcn_s_setprio(0);
            __bf16* ps = Ps + (kt & 1) * (BR * PP3);
#pragma unroll
            for (int r = 0; r < 4; r++) {
                float p00 = exp2f((S[0][0][0][r] + S[0][0][1][r]) * L2E - MSH);
                float p01 = exp2f((S[0][1][0][r] + S[0][1][1][r]) * L2E - MSH);
                float p10 = exp2f((S[1][0][0][r] + S[1][0][1][r]) * L2E - MSH);
                float p11 = exp2f((S[1][1][0][r] + S[1][1][1][r]) * L2E - MSH);
                __bf16 b00 = (__bf16)p00, b01 = (__bf16)p01;
                __bf16 b10 = (__bf16)p10, b11 = (__bf16)p11;
                int r0 = (rs0 + quad * 4 + r) * PP3;
                int r1 = (rs0 + 16 + quad * 4 + r) * PP3;
                ps[r0 + kg0 + l16]      = b00;
                ps[r0 + kg0 + 16 + l16] = b01;
                ps[r1 + kg0 + l16]      = b10;
                ps[r1 + kg0 + 16 + l16] = b11;
                lo0[r] += (float)b00 + (float)b01;
                lo1[r] += (float)b10 + (float)b11;
            }
            __builtin_amdgcn_sched_barrier(0);
            asm volatile("s_waitcnt vmcnt(0)");     // DMA(kt+1) retired
            asm volatile("s_waitcnt lgkmcnt(0)");   // Ps published
            __builtin_amdgcn_s_barrier();
            __builtin_amdgcn_sched_barrier(0);
        }

        // reduce l over the 16 key-column lanes, publish
#pragma unroll
        for (int r = 0; r < 4; r++)
#pragma unroll
            for (int m = 1; m < 16; m <<= 1) {
                lo0[r] += __shfl_xor(lo0[r], m, 16);
                lo1[r] += __shfl_xor(lo1[r], m, 16);
            }
        if (l16 == 0)
            for (int r = 0; r < 4; r++) {
                lpart[w >> 1][rs0 + quad * 4 + r]      = lo0[r];
                lpart[w >> 1][rs0 + 16 + quad * 4 + r] = lo1[r];
            }
        __syncthreads();    // E1: lpart visible; Ks reads done everywhere
        __syncthreads();    // E2: consumers wrote y_lds (producers idle)
    } else {
        // ==================================================== CONSUMER ====
        const int cv = w - 4;               // d-range cv*128 .. cv*128+127
        const __bf16* vpbase = vP + ((long)b * 128 * 32 + cv * 8) * 512 + lane * 8;

        f4 O[4][8];
#pragma unroll
        for (int rt = 0; rt < 4; rt++)
#pragma unroll
            for (int ct = 0; ct < 8; ct++) O[rt][ct] = (f4){0.f, 0.f, 0.f, 0.f};
        b8 vreg[16];

        __syncthreads();    // prologue barrier

        for (int kt = 0; kt < NIT2; kt++) {
            // a) DMA(kt+1) first (must be OLDER than V(kt) for the vmcnt(16))
            if (kt + 1 < NIT2) {
                const _Float16* kn = kbase + (long)(kt + 1) * BC2 * NQKV_;
                _Float16* kd = Ks + ((kt + 1) & 1) * KT3;
#pragma unroll
                for (int i = 0; i < 8; i++) {
                    int r = w * 8 + i;
                    gl_lds16(kn + (long)r * NQKV_ + lane * 8, kd + r * KP3);
                }
            }
            __builtin_amdgcn_sched_barrier(0);   // pin DMA-before-V issue order
            // b) PV(kt-1): wait V(kt-1) resident, then 64 MFMA
            if (kt > 0) {
                if (kt < NIT2 - 1) asm volatile("s_waitcnt vmcnt(8)");  // retires V(kt-1)
                else               asm volatile("s_waitcnt vmcnt(0)");  // no DMA issued
                const __bf16* ps = Ps + ((kt - 1) & 1) * (BR * PP3);
                __builtin_amdgcn_s_setprio(1);
#pragma unroll
                for (int rt = 0; rt < 4; rt++) {
                    b8 pa0 = *(const b8*)(ps + (rt * 16 + l16) * PP3 + quad * 8);
                    b8 pa1 = *(const b8*)(ps + (rt * 16 + l16) * PP3 + 32 + quad * 8);
#pragma unroll
                    for (int ct = 0; ct < 8; ct++) {
                        O[rt][ct] = __builtin_amdgcn_mfma_f32_16x16x32_bf16(pa0, vreg[ct],     O[rt][ct], 0, 0, 0);
                        O[rt][ct] = __builtin_amdgcn_mfma_f32_16x16x32_bf16(pa1, vreg[8 + ct], O[rt][ct], 0, 0, 0);
                    }
                }
                __builtin_amdgcn_s_setprio(0);
            }
            // c) issue V(kt): two 32-key fragment tiles, contiguous 8KB/wave
            {
                const __bf16* vs0 = vpbase + (long)(2 * kt) * (32 * 512);
#pragma unroll
                for (int ct = 0; ct < 8; ct++) {
                    vreg[ct]     = *(const b8*)(vs0 + ct * 512);
                    vreg[8 + ct] = *(const b8*)(vs0 + 32 * 512 + ct * 512);
                }
            }
            __builtin_amdgcn_sched_barrier(0);
            asm volatile("s_waitcnt vmcnt(16)");    // retire DMA(kt+1); V(kt) flies
            asm volatile("s_waitcnt lgkmcnt(0)");   // pa reads retired
            __builtin_amdgcn_s_barrier();
            __builtin_amdgcn_sched_barrier(0);
        }
        // final PV(NIT2-1)
        asm volatile("s_waitcnt vmcnt(0)");
        {
            const __bf16* ps = Ps + ((NIT2 - 1) & 1) * (BR * PP3);
#pragma unroll
            for (int rt = 0; rt < 4; rt++) {
                b8 pa0 = *(const b8*)(ps + (rt * 16 + l16) * PP3 + quad * 8);
                b8 pa1 = *(const b8*)(ps + (rt * 16 + l16) * PP3 + 32 + quad * 8);
#pragma unroll
                for (int ct = 0; ct < 8; ct++) {
                    O[rt][ct] = __builtin_amdgcn_mfma_f32_16x16x32_bf16(pa0, vreg[ct],     O[rt][ct], 0, 0, 0);
                    O[rt][ct] = __builtin_amdgcn_mfma_f32_16x16x32_bf16(pa1, vreg[8 + ct], O[rt][ct], 0, 0, 0);
                }
            }
        }
        __syncthreads();    // E1: lpart visible; all Ks reads done

        // normalize + write y tile into LDS (Ks reused as y_lds [64][YP] f16)
        {
            _Float16* y_lds = Ks;
#pragma unroll
            for (int rt = 0; rt < 4; rt++) {
                f4 l0 = *(const f4*)(&lpart[0][rt * 16 + quad * 4]);
                f4 l1 = *(const f4*)(&lpart[1][rt * 16 + quad * 4]);
                float li[4];
                for (int r = 0; r < 4; r++) li[r] = 1.f / (l0[r] + l1[r]);
                for (int ct = 0; ct < 8; ct++)
                    for (int r = 0; r < 4; r++)
                        y_lds[(rt * 16 + quad * 4 + r) * YP + cv * 128 + ct * 16 + l16] =
                            (_Float16)(O[rt][ct][r] * li[r]);
            }
        }
        __syncthreads();    // E2: y_lds visible
    }

    // ===== fused output projection: all 8 waves, out = y @ Wo + bo ========
    // wave w: rows 0..63 x cols w*64..w*64+63, K=512.  A = y_lds (f16),
    // B = woT rows (global, L2-hot).  Mapping identical to gemm_bt.
    {
        const _Float16* y_lds = Ks;
        f4 acc[4][4];
#pragma unroll
        for (int i = 0; i < 4; i++)
#pragma unroll
            for (int j = 0; j < 4; j++) acc[i][j] = (f4){0.f, 0.f, 0.f, 0.f};
        const _Float16* wb = woT + (long)(w * 64 + l16) * 512 + quad * 8;
#pragma unroll
        for (int ks = 0; ks < 16; ks++) {
            h8 af[4], bf[4];
#pragma unroll
            for (int i = 0; i < 4; i++)
                af[i] = *(const h8*)(y_lds + (i * 16 + l16) * YP + ks * 32 + quad * 8);
#pragma unroll
            for (int j = 0; j < 4; j++)
                bf[j] = *(const h8*)(wb + (long)j * 16 * 512 + ks * 32);
#pragma unroll
            for (int i = 0; i < 4; i++)
#pragma unroll
                for (int j = 0; j < 4; j++)
                    acc[i][j] = __builtin_amdgcn_mfma_f32_16x16x32_f16(af[i], bf[j], acc[i][j], 0, 0, 0);
        }
#pragma unroll
        for (int i = 0; i < 4; i++)
#pragma unroll
            for (int j = 0; j < 4; j++)
                for (int r = 0; r < 4; r++) {
                    long row = rowBase + q0 + i * 16 + quad * 4 + r;
                    int col = w * 64 + j * 16 + l16;
                    out[row * 512 + col] = acc[i][j][r] + bo[col];
                }
    }
}

// ----------------------------------------------------------------- launch ---
extern "C" void kernel_launch(void* const* d_in, const int* in_sizes, int n_in,
                              void* d_out, int out_size, void* d_ws, size_t ws_size,
                              hipStream_t stream)
{
    const float* x  = (const float*)d_in[0];
    const float* Wq = (const float*)d_in[1];
    const float* bq = (const float*)d_in[2];
    const float* Wk = (const float*)d_in[3];
    const float* bk = (const float*)d_in[4];
    const float* Wv = (const float*)d_in[5];
    const float* bv = (const float*)d_in[6];
    const float* Wo = (const float*)d_in[7];
    const float* bo = (const float*)d_in[8];
    float* out = (float*)d_out;

    char* ws = (char*)d_ws;
    _Float16* xh    = (_Float16*)(ws);                  // 16 MB
    _Float16* qkv   = (_Float16*)(ws + 16777216);       // 48 MB  [16384][1536] (V third unused)
    __bf16*   vP    = (__bf16*)(ws + 67108864);         // 16 MB  packed V (written by gemm1)
    _Float16* wqkvT = (_Float16*)(ws + 100663296);      // 1.5 MB
    _Float16* woT   = (_Float16*)(ws + 102236160);      // 0.5 MB
    float*    bqkv  = (float*)(ws + 102760448);         // 6 KB

    convert_all<<<2048, 256, 0, stream>>>(x, Wq, Wk, Wv, bq, bk, bv, Wo,
                                          xh, wqkvT, woT, bqkv);

    dim3 g1(128, 6);
    gemm_bt<true><<<g1, 512, 0, stream>>>(xh, wqkvT, bqkv, qkv, ROWS_, NQKV_, D_, vP);

    attn_kernel<<<256, 512, 0, stream>>>(qkv, vP, woT, bo, out);
}